// Round 1
// baseline (2623.651 us; speedup 1.0000x reference)
//
#include <hip/hip_runtime.h>
#include <hip/hip_bf16.h>

#define T_SEQ 256
#define BATCH 1024

__device__ __forceinline__ float sigmoid_fast(float x) {
    // exact formula; __expf(large)->inf gives 1/(1+inf)=0, correct saturation
    return 1.0f / (1.0f + __expf(-x));
}
__device__ __forceinline__ float tanh_fast(float x) {
    // tanh(x) = 1 - 2/(e^{2x}+1); saturates correctly at +/-inf, no NaN
    return 1.0f - 2.0f / (__expf(2.0f * x) + 1.0f);
}
__device__ __forceinline__ float bf16_to_f32(unsigned short u) {
    union { unsigned int i; float f; } v;
    v.i = ((unsigned int)u) << 16;
    return v.f;
}

// One kernel instance = one (layer, direction slab of RPB batch rows) for all T steps.
// Thread owns gate column j (weights in VGPRs) and computes RT=4 rows per step.
// D = input width, H = hidden, RPB = batch rows per block.
// IS_FIRST: input is fp32 [B][T][D]; else bf16 [T][B][D].
// SEQ_OUT: write bf16 [T][B][2H] every step; else only final h -> fp32 [B][2H].
template <int D, int H, int RPB, bool IS_FIRST, bool SEQ_OUT>
__global__ __launch_bounds__(256, 2) void lstm_layer(
    const void* __restrict__ xin,
    const float* __restrict__ Wf, const float* __restrict__ Uf, const float* __restrict__ bgf,
    const float* __restrict__ Wb, const float* __restrict__ Ub, const float* __restrict__ bgb,
    void* __restrict__ outp)
{
    constexpr int G4 = 4 * H;        // gate width
    constexpr int NG = 256 / G4;     // row-groups among threads
    constexpr int RT = RPB / NG;     // rows per thread in compute phase
    constexpr int KW = D + H;        // concat [x|h] width
    static_assert(RT == 4, "rows-per-thread must be 4");
    static_assert(RPB * H == 256, "update phase needs exactly 1 c per thread");
    static_assert(KW % 4 == 0, "float4 LDS reads");
    static_assert(IS_FIRST ? (RPB * D == 256) : (RPB * D == 1024), "x-load mapping");

    const int tid = threadIdx.x;
    const int dir = blockIdx.y;              // 0 fwd, 1 bwd
    const int b0  = blockIdx.x * RPB;

    const float* W  = dir ? Wb  : Wf;
    const float* U  = dir ? Ub  : Uf;
    const float* bg = dir ? bgb : bgf;

    const int j  = tid % G4;                 // gate column
    const int rg = tid / G4;                 // row group

    __shared__ float xh[RPB][KW];            // [x_t | h_{t-1}] per row
    __shared__ float zact[RPB][G4];          // activated gates

    // ---- load my weight column (stays in VGPRs; loads are lane-coalesced) ----
    float wu[KW];
#pragma unroll
    for (int k = 0; k < D; k++) wu[k] = W[k * G4 + j];
#pragma unroll
    for (int k = 0; k < H; k++) wu[D + k] = U[k * G4 + j];
    const float bj = bg[j];

    // ---- state (update-phase mapping: one (row,unit) per thread) ----
    const int ru = tid / H;
    const int uu = tid % H;
    float c = 0.0f;
    float hlast = 0.0f;
    xh[ru][D + uu] = 0.0f;                   // h_0 = 0
    __syncthreads();

    for (int s = 0; s < T_SEQ; s++) {
        const int t = dir ? (T_SEQ - 1 - s) : s;

        // ---- stage x_t into LDS ----
        if (IS_FIRST) {
            const int r = tid / D, f = tid % D;
            const float* xp = (const float*)xin;
            xh[r][f] = xp[((size_t)(b0 + r) * T_SEQ + t) * D + f];
        } else {
            constexpr int C4 = D / 4;
            const int r = tid / C4, c4 = tid % C4;
            const __hip_bfloat16* xp = (const __hip_bfloat16*)xin;
            const ushort4* srow = (const ushort4*)(xp + ((size_t)t * BATCH + (b0 + r)) * D);
            ushort4 v = srow[c4];
            float4 f4;
            f4.x = bf16_to_f32(v.x); f4.y = bf16_to_f32(v.y);
            f4.z = bf16_to_f32(v.z); f4.w = bf16_to_f32(v.w);
            ((float4*)&xh[r][0])[c4] = f4;
        }
        __syncthreads();   // B1: x_t and h_{t-1} visible

        // ---- z = [x|h] . wu + b ; activate ; stash in LDS ----
#pragma unroll
        for (int sr = 0; sr < RT; sr++) {
            const int r = rg * RT + sr;
            float a0 = bj, a1 = 0.0f, a2 = 0.0f, a3 = 0.0f;
            const float4* row = (const float4*)&xh[r][0];
#pragma unroll
            for (int k4 = 0; k4 < KW / 4; k4++) {
                float4 v = row[k4];            // same-addr broadcast across wave
                a0 = fmaf(wu[4 * k4 + 0], v.x, a0);
                a1 = fmaf(wu[4 * k4 + 1], v.y, a1);
                a2 = fmaf(wu[4 * k4 + 2], v.z, a2);
                a3 = fmaf(wu[4 * k4 + 3], v.w, a3);
            }
            const float a = (a0 + a1) + (a2 + a3);
            const bool is_g = (j >= 2 * H) && (j < 3 * H);   // gate order i,f,g,o
            zact[r][j] = is_g ? tanh_fast(a) : sigmoid_fast(a);
        }
        __syncthreads();   // B2: gates visible

        // ---- c,h update (one (row,unit) per thread; c lives in a register) ----
        {
            const float gi = zact[ru][uu];
            const float gf = zact[ru][H + uu];
            const float gg = zact[ru][2 * H + uu];
            const float go = zact[ru][3 * H + uu];
            c = fmaf(gf, c, gi * gg);
            const float h = go * tanh_fast(c);
            hlast = h;
            xh[ru][D + uu] = h;                              // h for next step
            if (SEQ_OUT) {
                __hip_bfloat16* op = (__hip_bfloat16*)outp;
                op[((size_t)t * BATCH + (b0 + ru)) * (2 * H) + dir * H + uu] =
                    __float2bfloat16(h);
            }
        }
        // next iteration's B1 orders h-write vs compute reads; x-load region disjoint
    }

    if (!SEQ_OUT) {
        float* op = (float*)outp;
        op[(size_t)(b0 + ru) * (2 * H) + dir * H + uu] = hlast;
    }
}

// Dense head: relu6(x@Wd1+bd1) @ Wd2 + bd2 -> softmax(2). One row per thread.
__global__ __launch_bounds__(256) void dense_head(
    const float* __restrict__ h3, const float* __restrict__ Wd1, const float* __restrict__ bd1,
    const float* __restrict__ Wd2, const float* __restrict__ bd2, float* __restrict__ out)
{
    const int b = blockIdx.x * blockDim.x + threadIdx.x;
    if (b >= BATCH) return;
    float x[32];
#pragma unroll
    for (int k = 0; k < 32; k++) x[k] = h3[b * 32 + k];
    float y[16];
#pragma unroll
    for (int jj = 0; jj < 16; jj++) {
        float a = bd1[jj];
#pragma unroll
        for (int k = 0; k < 32; k++) a = fmaf(x[k], Wd1[k * 16 + jj], a);
        y[jj] = fminf(fmaxf(a, 0.0f), 6.0f);
    }
    float l0 = bd2[0], l1 = bd2[1];
#pragma unroll
    for (int k = 0; k < 16; k++) {
        l0 = fmaf(y[k], Wd2[k * 2 + 0], l0);
        l1 = fmaf(y[k], Wd2[k * 2 + 1], l1);
    }
    const float m = fmaxf(l0, l1);
    const float e0 = __expf(l0 - m), e1 = __expf(l1 - m);
    const float inv = 1.0f / (e0 + e1);
    out[b * 2 + 0] = e0 * inv;
    out[b * 2 + 1] = e1 * inv;
}

extern "C" void kernel_launch(void* const* d_in, const int* in_sizes, int n_in,
                              void* d_out, int out_size, void* d_ws, size_t ws_size,
                              hipStream_t stream)
{
    const float* x   = (const float*)d_in[0];
    const float* W1f = (const float*)d_in[1];
    const float* U1f = (const float*)d_in[2];
    const float* b1f = (const float*)d_in[3];
    const float* W1b = (const float*)d_in[4];
    const float* U1b = (const float*)d_in[5];
    const float* b1b = (const float*)d_in[6];
    const float* W2f = (const float*)d_in[7];
    const float* U2f = (const float*)d_in[8];
    const float* b2f = (const float*)d_in[9];
    const float* W2b = (const float*)d_in[10];
    const float* U2b = (const float*)d_in[11];
    const float* b2b = (const float*)d_in[12];
    const float* W3f = (const float*)d_in[13];
    const float* U3f = (const float*)d_in[14];
    const float* b3f = (const float*)d_in[15];
    const float* W3b = (const float*)d_in[16];
    const float* U3b = (const float*)d_in[17];
    const float* b3b = (const float*)d_in[18];
    const float* Wd1 = (const float*)d_in[19];
    const float* bd1 = (const float*)d_in[20];
    const float* Wd2 = (const float*)d_in[21];
    const float* bd2 = (const float*)d_in[22];

    char* ws = (char*)d_ws;
    __hip_bfloat16* l1out = (__hip_bfloat16*)ws;                                // [T][B][128] bf16 = 64 MB
    __hip_bfloat16* l2out = (__hip_bfloat16*)(ws + (size_t)64 * 1024 * 1024);   // [T][B][64]  bf16 = 32 MB
    float*          h3    = (float*)(ws + (size_t)96 * 1024 * 1024);            // [B][32] fp32
    float*          out   = (float*)d_out;

    lstm_layer<64, 64, 4, true, true>
        <<<dim3(BATCH / 4, 2), 256, 0, stream>>>(x, W1f, U1f, b1f, W1b, U1b, b1b, l1out);
    lstm_layer<128, 32, 8, false, true>
        <<<dim3(BATCH / 8, 2), 256, 0, stream>>>(l1out, W2f, U2f, b2f, W2b, U2b, b2b, l2out);
    lstm_layer<64, 16, 16, false, false>
        <<<dim3(BATCH / 16, 2), 256, 0, stream>>>(l2out, W3f, U3f, b3f, W3b, U3b, b3b, h3);
    dense_head<<<dim3(BATCH / 256), 256, 0, stream>>>(h3, Wd1, bd1, Wd2, bd2, out);
}

// Round 2
// 1196.303 us; speedup vs baseline: 2.1931x; 2.1931x over previous
//
#include <hip/hip_runtime.h>
#include <hip/hip_bf16.h>

#define T_SEQ 256
#define BATCH 1024

typedef __attribute__((ext_vector_type(8))) short  short8;   // 8 bf16 in 4 VGPRs (MFMA A/B frag)
typedef __attribute__((ext_vector_type(4))) float  floatx4;  // MFMA C/D frag

__device__ __forceinline__ float sigmoid_fast(float x) {
    return 1.0f / (1.0f + __expf(-x));
}
__device__ __forceinline__ float tanh_fast(float x) {
    return 1.0f - 2.0f / (__expf(2.0f * x) + 1.0f);
}
__device__ __forceinline__ unsigned short f2bf(float f) {
    union { float f; unsigned int u; } v; v.f = f;
    unsigned int r = v.u + 0x7FFFu + ((v.u >> 16) & 1u);   // RNE
    return (unsigned short)(r >> 16);
}

// MFMA-based persistent LSTM layer: one block = 16 batch rows x one direction,
// all 256 time steps, 2 barriers per step.
//  - B operand (weights [KW x 4H] bf16) lives in VGPRs, loaded once.
//  - A operand ([x_t | h_{t-1}] bf16) staged in LDS; KS ds_read_b128 per wave per step.
//  - gates go through LDS (fp32) for the c/h update; c stays fp32 in registers.
// Fragment layouts (mfma_f32_16x16x32_bf16, HW-verified m89/m120):
//   A[m=lane&15][k=(lane>>4)*8+e]   B[k=(lane>>4)*8+e][n=lane&15]
//   C/D: col=lane&15, row=(lane>>4)*4+reg
template <int D, int H, bool IS_FIRST, bool SEQ_OUT>
__global__ __launch_bounds__(256, 2) void lstm_mfma(
    const void* __restrict__ xin,
    const float* __restrict__ Wf, const float* __restrict__ Uf, const float* __restrict__ bgf,
    const float* __restrict__ Wb, const float* __restrict__ Ub, const float* __restrict__ bgb,
    void* __restrict__ outp)
{
    constexpr int RPB = 16;               // batch rows per block (one MFMA m-tile)
    constexpr int KW  = D + H;            // concat width
    constexpr int KS  = (KW + 31) / 32;   // MFMA k-steps
    constexpr int KM  = KS * 32;          // padded k extent read by MFMA
    constexpr int KWP = KM + 8;           // LDS row stride (bf16) — +8 kills bank conflicts
    constexpr int G4  = 4 * H;            // gate width
    constexpr int NT  = G4 / 16;          // n-tiles
    constexpr int NTW = NT / 4;           // n-tiles per wave (4 waves)
    constexpr int G4P = G4 + 8;           // zact row stride (fp32)
    constexpr int CPT = RPB * H / 256;    // (row,unit) pairs per thread in update phase
    static_assert(NT % 4 == 0 && CPT >= 1 && D % 4 == 0, "shape");

    const int tid  = threadIdx.x;
    const int wid  = tid >> 6;
    const int lane = tid & 63;
    const int lm   = lane & 15;           // m (A) / n (B) / col (C)
    const int lq   = lane >> 4;           // k-quad / row-quad
    const int dir  = blockIdx.y;
    const int b0   = blockIdx.x * RPB;

    const float* W  = dir ? Wb  : Wf;
    const float* U  = dir ? Ub  : Uf;
    const float* bg = dir ? bgb : bgf;

    __shared__ unsigned short xh[RPB][KWP];   // [x_t | h] bf16
    __shared__ float zact[RPB][G4P];          // activated gates

    // ---- one-time: weight B-fragments into VGPRs ----
    short8 bfrag[NTW][KS];
    float  biasv[NTW];
    bool   isg[NTW];
#pragma unroll
    for (int nt = 0; nt < NTW; nt++) {
        const int tg = wid * NTW + nt;
        const int n  = tg * 16 + lm;
        biasv[nt] = bg[n];
        isg[nt]   = (tg >= 2 * (H / 16)) && (tg < 3 * (H / 16));  // gate order i,f,g,o
#pragma unroll
        for (int ks = 0; ks < KS; ks++) {
            short8 f;
#pragma unroll
            for (int e = 0; e < 8; e++) {
                const int k = ks * 32 + lq * 8 + e;
                float v = 0.0f;
                if (k < D)       v = W[k * G4 + n];
                else if (k < KW) v = U[(k - D) * G4 + n];
                f[e] = (short)f2bf(v);
            }
            bfrag[nt][ks] = f;
        }
    }

    // ---- zero h-region + k-padding of xh ----
    for (int idx = tid; idx < RPB * KWP; idx += 256) {
        const int r = idx / KWP, cc = idx % KWP;
        if (cc >= D) xh[r][cc] = 0;
    }

    // ---- per-thread recurrent state ----
    int   ru[CPT], uu[CPT];
    float cst[CPT], hlast[CPT];
#pragma unroll
    for (int q = 0; q < CPT; q++) {
        const int idx = q * 256 + tid;
        ru[q] = idx / H; uu[q] = idx % H;
        cst[q] = 0.0f; hlast[q] = 0.0f;
    }
    __syncthreads();

    for (int s = 0; s < T_SEQ; s++) {
        const int t = dir ? (T_SEQ - 1 - s) : s;

        // ---- stage x_t (bf16) into LDS ----
        if (IS_FIRST) {
            const float* xp = (const float*)xin;
            const int r = tid >> 4, f0 = (tid & 15) * 4;
            const float4 v = *(const float4*)(xp + ((size_t)(b0 + r) * T_SEQ + t) * D + f0);
            ushort4 u;
            u.x = f2bf(v.x); u.y = f2bf(v.y); u.z = f2bf(v.z); u.w = f2bf(v.w);
            *(ushort4*)&xh[r][f0] = u;
        } else if (D == 128) {
            const unsigned short* xp = (const unsigned short*)xin;
            const uint4 v = *(const uint4*)(xp + ((size_t)t * BATCH + b0) * 128 + tid * 8);
            const int r = tid >> 4, c = (tid & 15) * 8;
            *(uint4*)&xh[r][c] = v;
        } else {  // D == 64
            const unsigned short* xp = (const unsigned short*)xin;
            const ushort4 v = *(const ushort4*)(xp + ((size_t)t * BATCH + b0) * 64 + tid * 4);
            const int r = tid >> 4, c = (tid & 15) * 4;
            *(ushort4*)&xh[r][c] = v;
        }
        __syncthreads();   // B1: x_t + h_{t-1} visible; also orders update(t-1) before act(t)

        // ---- MFMA: z = [x|h] . [W;U] ----
        floatx4 acc[NTW];
#pragma unroll
        for (int nt = 0; nt < NTW; nt++) acc[nt] = (floatx4){0.f, 0.f, 0.f, 0.f};
        short8 af[KS];
#pragma unroll
        for (int ks = 0; ks < KS; ks++)
            af[ks] = *(const short8*)&xh[lm][ks * 32 + lq * 8];
#pragma unroll
        for (int ks = 0; ks < KS; ks++)
#pragma unroll
            for (int nt = 0; nt < NTW; nt++)
                acc[nt] = __builtin_amdgcn_mfma_f32_16x16x32_bf16(af[ks], bfrag[nt][ks], acc[nt], 0, 0, 0);

        // ---- activate, stash gates in LDS ----
#pragma unroll
        for (int nt = 0; nt < NTW; nt++) {
            const int n = (wid * NTW + nt) * 16 + lm;
#pragma unroll
            for (int r = 0; r < 4; r++) {
                const float z = acc[nt][r] + biasv[nt];
                zact[lq * 4 + r][n] = isg[nt] ? tanh_fast(z) : sigmoid_fast(z);
            }
        }
        __syncthreads();   // B2: gates visible

        // ---- fp32 c/h update; h -> LDS (bf16) + streamed output ----
#pragma unroll
        for (int q = 0; q < CPT; q++) {
            const float gi = zact[ru[q]][uu[q]];
            const float gf = zact[ru[q]][H + uu[q]];
            const float gg = zact[ru[q]][2 * H + uu[q]];
            const float go = zact[ru[q]][3 * H + uu[q]];
            cst[q] = fmaf(gf, cst[q], gi * gg);
            const float h = go * tanh_fast(cst[q]);
            hlast[q] = h;
            xh[ru[q]][D + uu[q]] = f2bf(h);
            if (SEQ_OUT) {
                unsigned short* op = (unsigned short*)outp;
                op[((size_t)t * BATCH + b0 + ru[q]) * (2 * H) + dir * H + uu[q]] = f2bf(h);
            }
        }
        // next iteration's B1 orders h/zact hazards
    }

    if (!SEQ_OUT) {
        float* op = (float*)outp;
#pragma unroll
        for (int q = 0; q < CPT; q++)
            op[(size_t)(b0 + ru[q]) * (2 * H) + dir * H + uu[q]] = hlast[q];
    }
}

// Dense head: relu6(x@Wd1+bd1) @ Wd2 + bd2 -> softmax(2). One row per thread.
__global__ __launch_bounds__(256) void dense_head(
    const float* __restrict__ h3, const float* __restrict__ Wd1, const float* __restrict__ bd1,
    const float* __restrict__ Wd2, const float* __restrict__ bd2, float* __restrict__ out)
{
    const int b = blockIdx.x * blockDim.x + threadIdx.x;
    if (b >= BATCH) return;
    float x[32];
#pragma unroll
    for (int k = 0; k < 32; k++) x[k] = h3[b * 32 + k];
    float y[16];
#pragma unroll
    for (int jj = 0; jj < 16; jj++) {
        float a = bd1[jj];
#pragma unroll
        for (int k = 0; k < 32; k++) a = fmaf(x[k], Wd1[k * 16 + jj], a);
        y[jj] = fminf(fmaxf(a, 0.0f), 6.0f);
    }
    float l0 = bd2[0], l1 = bd2[1];
#pragma unroll
    for (int k = 0; k < 16; k++) {
        l0 = fmaf(y[k], Wd2[k * 2 + 0], l0);
        l1 = fmaf(y[k], Wd2[k * 2 + 1], l1);
    }
    const float m = fmaxf(l0, l1);
    const float e0 = __expf(l0 - m), e1 = __expf(l1 - m);
    const float inv = 1.0f / (e0 + e1);
    out[b * 2 + 0] = e0 * inv;
    out[b * 2 + 1] = e1 * inv;
}

extern "C" void kernel_launch(void* const* d_in, const int* in_sizes, int n_in,
                              void* d_out, int out_size, void* d_ws, size_t ws_size,
                              hipStream_t stream)
{
    const float* x   = (const float*)d_in[0];
    const float* W1f = (const float*)d_in[1];
    const float* U1f = (const float*)d_in[2];
    const float* b1f = (const float*)d_in[3];
    const float* W1b = (const float*)d_in[4];
    const float* U1b = (const float*)d_in[5];
    const float* b1b = (const float*)d_in[6];
    const float* W2f = (const float*)d_in[7];
    const float* U2f = (const float*)d_in[8];
    const float* b2f = (const float*)d_in[9];
    const float* W2b = (const float*)d_in[10];
    const float* U2b = (const float*)d_in[11];
    const float* b2b = (const float*)d_in[12];
    const float* W3f = (const float*)d_in[13];
    const float* U3f = (const float*)d_in[14];
    const float* b3f = (const float*)d_in[15];
    const float* W3b = (const float*)d_in[16];
    const float* U3b = (const float*)d_in[17];
    const float* b3b = (const float*)d_in[18];
    const float* Wd1 = (const float*)d_in[19];
    const float* bd1 = (const float*)d_in[20];
    const float* Wd2 = (const float*)d_in[21];
    const float* bd2 = (const float*)d_in[22];

    char* ws = (char*)d_ws;
    void* l1out = (void*)ws;                                  // [T][B][128] bf16 = 64 MB
    void* l2out = (void*)(ws + (size_t)64 * 1024 * 1024);     // [T][B][64]  bf16 = 32 MB
    float* h3   = (float*)(ws + (size_t)96 * 1024 * 1024);    // [B][32] fp32
    float* out  = (float*)d_out;

    lstm_mfma<64, 64, true, true>
        <<<dim3(BATCH / 16, 2), 256, 0, stream>>>(x, W1f, U1f, b1f, W1b, U1b, b1b, l1out);
    lstm_mfma<128, 32, false, true>
        <<<dim3(BATCH / 16, 2), 256, 0, stream>>>(l1out, W2f, U2f, b2f, W2b, U2b, b2b, l2out);
    lstm_mfma<64, 16, false, false>
        <<<dim3(BATCH / 16, 2), 256, 0, stream>>>(l2out, W3f, U3f, b3f, W3b, U3b, b3b, h3);
    dense_head<<<dim3(BATCH / 256), 256, 0, stream>>>(h3, Wd1, bd1, Wd2, bd2, out);
}

// Round 3
// 980.304 us; speedup vs baseline: 2.6764x; 1.2203x over previous
//
#include <hip/hip_runtime.h>
#include <hip/hip_bf16.h>

#define T_SEQ 256
#define BATCH 1024

typedef __attribute__((ext_vector_type(8))) short  short8;   // 8 bf16 (MFMA A/B frag)
typedef __attribute__((ext_vector_type(4))) float  floatx4;  // MFMA C/D frag

template <int P> struct IC { static constexpr int v = P; };

__device__ __forceinline__ float sigmoid_fast(float x) {
    return 1.0f / (1.0f + __expf(-x));
}
__device__ __forceinline__ float tanh_fast(float x) {
    return 1.0f - 2.0f / (__expf(2.0f * x) + 1.0f);   // saturates correctly at +/-inf
}
__device__ __forceinline__ unsigned short f2bf(float f) {
    union { float f; unsigned int u; } v; v.f = f;
    unsigned int r = v.u + 0x7FFFu + ((v.u >> 16) & 1u);   // RNE
    return (unsigned short)(r >> 16);
}
// Barrier WITHOUT the compiler's vmcnt(0) drain (CK block_sync_lds pattern):
// LDS writes are lgkm-drained; global prefetch loads / h-history stores stay in flight.
__device__ __forceinline__ void sync_lds() {
    asm volatile("s_waitcnt lgkmcnt(0)\n\ts_barrier" ::: "memory");
}

// Persistent MFMA LSTM layer, ONE barrier per step.
//  - wave (mt,ug) owns m-tile mt and unit-group ug: its 4 gate tiles {g*UG+ug} have
//    identical C row/col lane-mapping -> i,f,g,o for a (row,unit) are all in ONE lane.
//    c/h update is pure-register; gates never touch LDS.
//  - h lives in a ping-pong LDS buffer (bf16, padded stride); x is prefetched 2 steps
//    ahead straight into A-fragment VGPRs (layer 1 converts fp32->bf16 off-path).
// Fragment maps (mfma_f32_16x16x32_bf16, HW-verified): A[m=lane&15][k=(lane>>4)*8+e],
// B[k=(lane>>4)*8+e][n=lane&15], C: col=lane&15, row=(lane>>4)*4+reg.
template <int D, int H, bool IS_FIRST, bool SEQ_OUT>
__global__ __launch_bounds__(256, 1) void lstm_mfma(
    const void* __restrict__ xin,
    const float* __restrict__ Wf, const float* __restrict__ Uf, const float* __restrict__ bgf,
    const float* __restrict__ Wb, const float* __restrict__ Ub, const float* __restrict__ bgb,
    void* __restrict__ outp)
{
    constexpr int UG  = H / 16;            // unit groups (1,2,4)
    constexpr int MTB = 4 / UG;            // m-tiles per block (4 waves total)
    constexpr int RPB = 16 * MTB;          // batch rows per block
    constexpr int KSx = D / 32;            // x k-steps
    constexpr int KSh = (H + 31) / 32;     // h k-steps (H=16 padded to 32)
    constexpr int KS  = KSx + KSh;
    constexpr int HP  = (H < 32 ? 32 : H) + 8;   // padded h-row stride (u16); 72/40 -> conflict-free b128
    constexpr int G4  = 4 * H;
    static_assert(UG * 16 == H && D % 32 == 0, "shape");

    const int tid  = threadIdx.x;
    const int wid  = tid >> 6;
    const int lane = tid & 63;
    const int lm   = lane & 15;
    const int lq   = lane >> 4;
    const int mt   = wid / UG;
    const int ug   = wid % UG;
    const int dir  = blockIdx.y;
    const int b0   = blockIdx.x * RPB;

    const float* W  = dir ? Wb  : Wf;
    const float* U  = dir ? Ub  : Uf;
    const float* bg = dir ? bgb : bgf;

    __shared__ __align__(16) unsigned short hbuf[2][RPB][HP];

    // ---- one-time: weight B-frags (gate-major) + biases into VGPRs ----
    short8 bw[4][KS];
#pragma unroll
    for (int g = 0; g < 4; g++) {
        const int n = (g * UG + ug) * 16 + lm;
#pragma unroll
        for (int ks = 0; ks < KS; ks++) {
            short8 f;
#pragma unroll
            for (int e = 0; e < 8; e++) {
                const int k = ks * 32 + lq * 8 + e;
                float v = 0.0f;
                if (k < D)          v = W[k * G4 + n];
                else if (k < D + H) v = U[(k - D) * G4 + n];
                f[e] = (short)f2bf(v);
            }
            bw[g][ks] = f;
        }
    }
    float bb[4];
#pragma unroll
    for (int g = 0; g < 4; g++) bb[g] = bg[g * H + ug * 16 + lm];

    // zero both h ping-pong buffers (h0 = 0; L3's k-padding stays 0 forever)
    for (int idx = tid; idx < 2 * RPB * HP; idx += 256)
        ((unsigned short*)hbuf)[idx] = 0;

    float cst[4] = {0.f, 0.f, 0.f, 0.f};
    float hl[4]  = {0.f, 0.f, 0.f, 0.f};
    const int grow = b0 + mt * 16 + lm;    // global batch row for this lane's A-frags

    short8 frx[2][KSx];                    // x A-frags, ping-pong
    float4 raw[2 * KSx];                   // fp32 staging (layer 1 only; DCE'd otherwise)

    auto tof = [&](int s) -> int {
        const int sc = s < T_SEQ ? s : T_SEQ - 1;   // clamp (loaded-but-unused tail)
        return dir ? (T_SEQ - 1 - sc) : sc;
    };

    // layer-1: fp32 x -> raw regs
    auto load_raw = [&](int s) {
        const int t = tof(s);
        const float* xp = (const float*)xin;
        const size_t base = ((size_t)grow * T_SEQ + t) * D + lq * 8;
#pragma unroll
        for (int ks = 0; ks < KSx; ks++) {
            raw[ks * 2 + 0] = *(const float4*)(xp + base + ks * 32 + 0);
            raw[ks * 2 + 1] = *(const float4*)(xp + base + ks * 32 + 4);
        }
    };
    auto conv = [&](auto pc) {             // raw -> frx[P] (bf16)
        constexpr int P = decltype(pc)::v;
#pragma unroll
        for (int ks = 0; ks < KSx; ks++) {
            short8 f;
#pragma unroll
            for (int e = 0; e < 4; e++) {
                f[e]     = (short)f2bf(((const float*)&raw[ks * 2 + 0])[e]);
                f[4 + e] = (short)f2bf(((const float*)&raw[ks * 2 + 1])[e]);
            }
            frx[P][ks] = f;
        }
    };
    // bf16 layers: load A-frags straight from global (layout matches fragment order)
    auto load_frx = [&](auto pc, int s) {
        constexpr int P = decltype(pc)::v;
        const int t = tof(s);
        const unsigned short* xp = (const unsigned short*)xin;
        const size_t base = ((size_t)t * BATCH + grow) * D + lq * 8;
#pragma unroll
        for (int ks = 0; ks < KSx; ks++)
            frx[P][ks] = *(const short8*)(xp + base + ks * 32);
    };

    if (IS_FIRST) {
        load_raw(0); conv(IC<0>{}); load_raw(1);
    } else {
        load_frx(IC<0>{}, 0); load_frx(IC<1>{}, 1);
    }
    __syncthreads();   // full barrier once (covers hbuf zero-init)

    auto step = [&](auto pc, int s) {
        constexpr int P = decltype(pc)::v;
        const int t = tof(s);

        // h A-frags from LDS (issued first; x-MFMAs below overlap the lgkm latency)
        short8 fh[KSh];
#pragma unroll
        for (int ks = 0; ks < KSh; ks++)
            fh[ks] = *(const short8*)&hbuf[P][mt * 16 + lm][ks * 32 + lq * 8];

        floatx4 acc[4];
#pragma unroll
        for (int g = 0; g < 4; g++) acc[g] = (floatx4){0.f, 0.f, 0.f, 0.f};

        // x-part MFMAs (register A-frags, no LDS dependency)
#pragma unroll
        for (int ks = 0; ks < KSx; ks++)
#pragma unroll
            for (int g = 0; g < 4; g++)
                acc[g] = __builtin_amdgcn_mfma_f32_16x16x32_bf16(frx[P][ks], bw[g][ks], acc[g], 0, 0, 0);

        // prefetch pipeline: frags for s+1 ready; issue loads for s+2
        if (IS_FIRST) { conv(IC<P ^ 1>{}); load_raw(s + 2); }
        else          { load_frx(pc, s + 2); }

        // h-part MFMAs
#pragma unroll
        for (int ks = 0; ks < KSh; ks++)
#pragma unroll
            for (int g = 0; g < 4; g++)
                acc[g] = __builtin_amdgcn_mfma_f32_16x16x32_bf16(fh[ks], bw[g][KSx + ks], acc[g], 0, 0, 0);

        // pure-register gate activation + c/h update (all 4 gates live in this lane)
#pragma unroll
        for (int r = 0; r < 4; r++) {
            const float gi = sigmoid_fast(acc[0][r] + bb[0]);
            const float gf = sigmoid_fast(acc[1][r] + bb[1]);
            const float gg = tanh_fast   (acc[2][r] + bb[2]);
            const float go = sigmoid_fast(acc[3][r] + bb[3]);
            cst[r] = fmaf(gf, cst[r], gi * gg);
            const float h = go * tanh_fast(cst[r]);
            hl[r] = h;
            const int row = mt * 16 + lq * 4 + r;
            const int u   = ug * 16 + lm;
            hbuf[P ^ 1][row][u] = f2bf(h);
            if (SEQ_OUT)
                ((unsigned short*)outp)[((size_t)t * BATCH + b0 + row) * (2 * H) + dir * H + u] = f2bf(h);
        }
        sync_lds();   // lgkm-only drain; prefetch loads & h stores stay in flight
    };

    for (int s = 0; s < T_SEQ; s += 2) {
        step(IC<0>{}, s);
        step(IC<1>{}, s + 1);
    }

    if (!SEQ_OUT) {
        float* op = (float*)outp;
#pragma unroll
        for (int r = 0; r < 4; r++) {
            const int row = mt * 16 + lq * 4 + r;
            const int u   = ug * 16 + lm;
            op[(size_t)(b0 + row) * (2 * H) + dir * H + u] = hl[r];
        }
    }
}

// Dense head: relu6(x@Wd1+bd1) @ Wd2 + bd2 -> softmax(2). One row per thread.
__global__ __launch_bounds__(256) void dense_head(
    const float* __restrict__ h3, const float* __restrict__ Wd1, const float* __restrict__ bd1,
    const float* __restrict__ Wd2, const float* __restrict__ bd2, float* __restrict__ out)
{
    const int b = blockIdx.x * blockDim.x + threadIdx.x;
    if (b >= BATCH) return;
    float x[32];
#pragma unroll
    for (int k = 0; k < 32; k++) x[k] = h3[b * 32 + k];
    float y[16];
#pragma unroll
    for (int jj = 0; jj < 16; jj++) {
        float a = bd1[jj];
#pragma unroll
        for (int k = 0; k < 32; k++) a = fmaf(x[k], Wd1[k * 16 + jj], a);
        y[jj] = fminf(fmaxf(a, 0.0f), 6.0f);
    }
    float l0 = bd2[0], l1 = bd2[1];
#pragma unroll
    for (int k = 0; k < 16; k++) {
        l0 = fmaf(y[k], Wd2[k * 2 + 0], l0);
        l1 = fmaf(y[k], Wd2[k * 2 + 1], l1);
    }
    const float m = fmaxf(l0, l1);
    const float e0 = __expf(l0 - m), e1 = __expf(l1 - m);
    const float inv = 1.0f / (e0 + e1);
    out[b * 2 + 0] = e0 * inv;
    out[b * 2 + 1] = e1 * inv;
}

extern "C" void kernel_launch(void* const* d_in, const int* in_sizes, int n_in,
                              void* d_out, int out_size, void* d_ws, size_t ws_size,
                              hipStream_t stream)
{
    const float* x   = (const float*)d_in[0];
    const float* W1f = (const float*)d_in[1];
    const float* U1f = (const float*)d_in[2];
    const float* b1f = (const float*)d_in[3];
    const float* W1b = (const float*)d_in[4];
    const float* U1b = (const float*)d_in[5];
    const float* b1b = (const float*)d_in[6];
    const float* W2f = (const float*)d_in[7];
    const float* U2f = (const float*)d_in[8];
    const float* b2f = (const float*)d_in[9];
    const float* W2b = (const float*)d_in[10];
    const float* U2b = (const float*)d_in[11];
    const float* b2b = (const float*)d_in[12];
    const float* W3f = (const float*)d_in[13];
    const float* U3f = (const float*)d_in[14];
    const float* b3f = (const float*)d_in[15];
    const float* W3b = (const float*)d_in[16];
    const float* U3b = (const float*)d_in[17];
    const float* b3b = (const float*)d_in[18];
    const float* Wd1 = (const float*)d_in[19];
    const float* bd1 = (const float*)d_in[20];
    const float* Wd2 = (const float*)d_in[21];
    const float* bd2 = (const float*)d_in[22];

    char* ws = (char*)d_ws;
    void* l1out = (void*)ws;                                  // [T][B][128] bf16 = 64 MB
    void* l2out = (void*)(ws + (size_t)64 * 1024 * 1024);     // [T][B][64]  bf16 = 32 MB
    float* h3   = (float*)(ws + (size_t)96 * 1024 * 1024);    // [B][32] fp32
    float* out  = (float*)d_out;

    lstm_mfma<64, 64, true, true>      // UG=4, RPB=16
        <<<dim3(BATCH / 16, 2), 256, 0, stream>>>(x, W1f, U1f, b1f, W1b, U1b, b1b, l1out);
    lstm_mfma<128, 32, false, true>    // UG=2, RPB=32
        <<<dim3(BATCH / 32, 2), 256, 0, stream>>>(l1out, W2f, U2f, b2f, W2b, U2b, b2b, l2out);
    lstm_mfma<64, 16, false, false>    // UG=1, RPB=64
        <<<dim3(BATCH / 64, 2), 256, 0, stream>>>(l2out, W3f, U3f, b3f, W3b, U3b, b3b, h3);
    dense_head<<<dim3(BATCH / 256), 256, 0, stream>>>(h3, Wd1, bd1, Wd2, bd2, out);
}